// Round 1
// baseline (1418.071 us; speedup 1.0000x reference)
//
#include <hip/hip_runtime.h>
#include <hip/hip_bf16.h>
#include <stdint.h>

#define S_LEN 2048
#define EMBED 2048
#define NHEADS 16
#define HDIM 128

typedef __attribute__((ext_vector_type(8))) short bf16x8;
typedef __attribute__((ext_vector_type(4))) float f32x4;

static __device__ __forceinline__ unsigned short f2b(float f) {
    union { float f; unsigned u; } x; x.f = f;
    unsigned r = x.u + 0x7fffu + ((x.u >> 16) & 1u);
    return (unsigned short)(r >> 16);
}

// C[M,N] = A[M,K] @ W[K,N] + bias.  A: fp32 or bf16(ushort bits). C: fp32 or bf16.
// Tiles: 128x128, BK=32. 256 threads = 4 waves in 2x2, each wave 64x64 via 4x4 MFMA tiles.
template <bool A_BF16, bool OUT_BF16>
__global__ __launch_bounds__(256) void gemm_bias(
    const void* __restrict__ Av, const float* __restrict__ W,
    const float* __restrict__ bias, void* __restrict__ Cv,
    int M, int N, int K)
{
    __shared__ unsigned short As[128][48];  // 32 k-cols used; stride 48 (96B, 16B-mult)
    __shared__ unsigned short Bs[128][48];  // transposed: [n][k]

    const int tid  = threadIdx.x;
    const int lane = tid & 63;
    const int wave = tid >> 6;
    const int lm   = lane & 15;
    const int quad = lane >> 4;
    const int wm = wave >> 1, wn = wave & 1;
    const int bm = blockIdx.y * 128, bn = blockIdx.x * 128;

    const float* Af = (const float*)Av;
    const unsigned short* Ab = (const unsigned short*)Av;

    f32x4 acc[4][4];
#pragma unroll
    for (int i = 0; i < 4; i++)
#pragma unroll
        for (int j = 0; j < 4; j++) acc[i][j] = (f32x4){0.f, 0.f, 0.f, 0.f};

    for (int k0 = 0; k0 < K; k0 += 32) {
        // stage A tile 128x32 (8 consecutive k per thread -> one b128 LDS write)
#pragma unroll
        for (int p = 0; p < 2; p++) {
            int o = p * 256 + tid;
            int row = o >> 2;
            int kc = (o & 3) * 8;
            if (A_BF16) {
                const uint4* g = (const uint4*)(Ab + (size_t)(bm + row) * K + k0 + kc);
                *(uint4*)&As[row][kc] = *g;
            } else {
                const float* g = Af + (size_t)(bm + row) * K + k0 + kc;
                unsigned short t8[8];
#pragma unroll
                for (int j = 0; j < 8; j++) t8[j] = f2b(g[j]);
                *(uint4*)&As[row][kc] = *(uint4*)t8;
            }
        }
        // stage B tile 32x128, transposed into Bs[n][k]
#pragma unroll
        for (int p = 0; p < 4; p++) {
            int o = p * 256 + tid;
            int kr = o >> 5;
            int n4 = (o & 31) * 4;
            const float4 v = *(const float4*)(W + (size_t)(k0 + kr) * N + bn + n4);
            Bs[n4 + 0][kr] = f2b(v.x);
            Bs[n4 + 1][kr] = f2b(v.y);
            Bs[n4 + 2][kr] = f2b(v.z);
            Bs[n4 + 3][kr] = f2b(v.w);
        }
        __syncthreads();

        bf16x8 af[4], bf[4];
#pragma unroll
        for (int mi = 0; mi < 4; mi++)
            af[mi] = *(const bf16x8*)&As[wm * 64 + mi * 16 + lm][quad * 8];
#pragma unroll
        for (int ni = 0; ni < 4; ni++)
            bf[ni] = *(const bf16x8*)&Bs[wn * 64 + ni * 16 + lm][quad * 8];
#pragma unroll
        for (int mi = 0; mi < 4; mi++)
#pragma unroll
            for (int ni = 0; ni < 4; ni++)
                acc[mi][ni] = __builtin_amdgcn_mfma_f32_16x16x32_bf16(
                    af[mi], bf[ni], acc[mi][ni], 0, 0, 0);
        __syncthreads();
    }

    // epilogue: C row = quad*4+r, col = lane&15
#pragma unroll
    for (int mi = 0; mi < 4; mi++) {
#pragma unroll
        for (int ni = 0; ni < 4; ni++) {
            int col = bn + wn * 64 + ni * 16 + lm;
            float bv = bias[col];
#pragma unroll
            for (int r = 0; r < 4; r++) {
                int row = bm + wm * 64 + mi * 16 + quad * 4 + r;
                float v = acc[mi][ni][r] + bv;
                if (OUT_BF16)
                    ((unsigned short*)Cv)[(size_t)row * N + col] = f2b(v);
                else
                    ((float*)Cv)[(size_t)row * N + col] = v;
            }
        }
    }
}

// Flash-style MQA attention. Q[B*S, D] bf16 (head slice h*128..), K/V [B*S, 128] bf16.
// Output O [B*S, D] bf16 (same head-sliced layout). Block: 4 waves; wave w owns 16 Q rows.
__global__ __launch_bounds__(256) void mqa_attn(
    const unsigned short* __restrict__ Qb,
    const unsigned short* __restrict__ Kb,
    const unsigned short* __restrict__ Vb,
    unsigned short* __restrict__ Ob)
{
    __shared__ unsigned short Qs[64][136];     // [q][hd], stride 272B (16B-mult)
    __shared__ unsigned short Ks[32][136];     // [t][hd]
    __shared__ unsigned short Vs[128][48];     // [hd][t], transposed for B-operand
    __shared__ unsigned short Ps[4][16][48];   // per-wave P round-trip, A-layout

    const int tid  = threadIdx.x;
    const int lane = tid & 63;
    const int w    = tid >> 6;
    const int lm   = lane & 15;
    const int quad = lane >> 4;
    const int q0 = blockIdx.x * 64;
    const int h  = blockIdx.y;
    const int b  = blockIdx.z;
    const size_t bS = (size_t)b * S_LEN;
    const float scale = 0.08838834764831845f;  // 1/sqrt(128)

    // stage Q tile (64 x 128)
#pragma unroll
    for (int p = 0; p < 4; p++) {
        int idx = p * 256 + tid;
        int row = idx >> 4;
        int c8 = (idx & 15) * 8;
        const uint4* g = (const uint4*)(Qb + (bS + q0 + row) * EMBED + h * HDIM + c8);
        *(uint4*)&Qs[row][c8] = *g;
    }

    f32x4 oacc[8];
#pragma unroll
    for (int i = 0; i < 8; i++) oacc[i] = (f32x4){0.f, 0.f, 0.f, 0.f};
    float mrow[4], lrow[4];
#pragma unroll
    for (int r = 0; r < 4; r++) { mrow[r] = -INFINITY; lrow[r] = 0.f; }

    __syncthreads();

    for (int t0 = 0; t0 < S_LEN; t0 += 32) {
        // stage K tile [32][128]
#pragma unroll
        for (int p = 0; p < 2; p++) {
            int idx = p * 256 + tid;
            int row = idx >> 4;
            int c8 = (idx & 15) * 8;
            const uint4* g = (const uint4*)(Kb + (bS + t0 + row) * HDIM + c8);
            *(uint4*)&Ks[row][c8] = *g;
        }
        // stage V tile transposed -> Vs[hd][t]
        {
            int t = tid >> 3;
            int hd0 = (tid & 7) * 16;
            const unsigned short* g = Vb + (bS + t0 + t) * HDIM + hd0;
            uint4 v0 = *(const uint4*)g;
            uint4 v1 = *(const uint4*)(g + 8);
            unsigned short tmp[16];
            *(uint4*)&tmp[0] = v0;
            *(uint4*)&tmp[8] = v1;
#pragma unroll
            for (int j = 0; j < 16; j++) Vs[hd0 + j][t] = tmp[j];
        }
        __syncthreads();

        // S(16x32) = Q_wave(16x128) @ K^T ; two 16-col n-tiles
        f32x4 sacc[2];
        sacc[0] = (f32x4){0.f, 0.f, 0.f, 0.f};
        sacc[1] = (f32x4){0.f, 0.f, 0.f, 0.f};
#pragma unroll
        for (int ks = 0; ks < 4; ks++) {
            bf16x8 aq  = *(const bf16x8*)&Qs[w * 16 + lm][ks * 32 + quad * 8];
            bf16x8 bk0 = *(const bf16x8*)&Ks[lm][ks * 32 + quad * 8];
            bf16x8 bk1 = *(const bf16x8*)&Ks[16 + lm][ks * 32 + quad * 8];
            sacc[0] = __builtin_amdgcn_mfma_f32_16x16x32_bf16(aq, bk0, sacc[0], 0, 0, 0);
            sacc[1] = __builtin_amdgcn_mfma_f32_16x16x32_bf16(aq, bk1, sacc[1], 0, 0, 0);
        }

        // online softmax; C-layout row quad*4+r lives across the 16 lanes of this quad
#pragma unroll
        for (int r = 0; r < 4; r++) {
            float s0 = sacc[0][r] * scale, s1 = sacc[1][r] * scale;
            float mx = fmaxf(s0, s1);
            for (int off = 1; off < 16; off <<= 1) mx = fmaxf(mx, __shfl_xor(mx, off));
            float mnew = fmaxf(mrow[r], mx);
            float al = __expf(mrow[r] - mnew);
            float p0 = __expf(s0 - mnew), p1 = __expf(s1 - mnew);
            float rs = p0 + p1;
            for (int off = 1; off < 16; off <<= 1) rs += __shfl_xor(rs, off);
            lrow[r] = lrow[r] * al + rs;
            mrow[r] = mnew;
#pragma unroll
            for (int hdt = 0; hdt < 8; hdt++) oacc[hdt][r] *= al;
            Ps[w][quad * 4 + r][lm]      = f2b(p0);
            Ps[w][quad * 4 + r][16 + lm] = f2b(p1);
        }
        __syncthreads();

        // O(16x128) += P(16x32) @ V(32x128)
        {
            bf16x8 ap = *(const bf16x8*)&Ps[w][lm][quad * 8];
#pragma unroll
            for (int hdt = 0; hdt < 8; hdt++) {
                bf16x8 bv = *(const bf16x8*)&Vs[hdt * 16 + lm][quad * 8];
                oacc[hdt] = __builtin_amdgcn_mfma_f32_16x16x32_bf16(ap, bv, oacc[hdt], 0, 0, 0);
            }
        }
        __syncthreads();
    }

    // epilogue: divide by l, store bf16 at [b, s, h*128 + hd]
#pragma unroll
    for (int r = 0; r < 4; r++) {
        float inv = 1.f / lrow[r];
        int s = q0 + w * 16 + quad * 4 + r;
#pragma unroll
        for (int hdt = 0; hdt < 8; hdt++) {
            Ob[(bS + s) * EMBED + h * HDIM + hdt * 16 + lm] = f2b(oacc[hdt][r] * inv);
        }
    }
}

extern "C" void kernel_launch(void* const* d_in, const int* in_sizes, int n_in,
                              void* d_out, int out_size, void* d_ws, size_t ws_size,
                              hipStream_t stream) {
    const float* query = (const float*)d_in[0];
    const float* key   = (const float*)d_in[1];
    const float* value = (const float*)d_in[2];
    const float* Wq = (const float*)d_in[3];
    const float* bq = (const float*)d_in[4];
    const float* Wk = (const float*)d_in[5];
    const float* bk = (const float*)d_in[6];
    const float* Wv = (const float*)d_in[7];
    const float* bv = (const float*)d_in[8];
    const float* Wo = (const float*)d_in[9];
    const float* bo = (const float*)d_in[10];
    float* out = (float*)d_out;

    // workspace (bf16 intermediates): Q 16.8MB, K 1MB, V 1MB, attn-out 16.8MB
    unsigned short* Qb  = (unsigned short*)d_ws;
    unsigned short* Kb  = Qb + (size_t)4096 * 2048;
    unsigned short* Vb  = Kb + (size_t)4096 * 128;
    unsigned short* AOb = Vb + (size_t)4096 * 128;

    dim3 blk(256);
    // Q = query @ Wq + bq   [4096,2048]
    gemm_bias<false, true><<<dim3(16, 32), blk, 0, stream>>>(query, Wq, bq, Qb, 4096, 2048, 2048);
    // K = key @ Wk + bk     [4096,128]
    gemm_bias<false, true><<<dim3(1, 32), blk, 0, stream>>>(key, Wk, bk, Kb, 4096, 128, 2048);
    // V = value @ Wv + bv   [4096,128]
    gemm_bias<false, true><<<dim3(1, 32), blk, 0, stream>>>(value, Wv, bv, Vb, 4096, 128, 2048);
    // attention
    mqa_attn<<<dim3(S_LEN / 64, NHEADS, 2), blk, 0, stream>>>(Qb, Kb, Vb, AOb);
    // out = AO @ Wo + bo    [4096,2048] fp32
    gemm_bias<true, false><<<dim3(16, 32), blk, 0, stream>>>(AOb, Wo, bo, out, 4096, 2048, 2048);
}

// Round 2
// 413.480 us; speedup vs baseline: 3.4296x; 3.4296x over previous
//
#include <hip/hip_runtime.h>
#include <stdint.h>

#define S_LEN 2048
#define EMBED 2048
#define NHEADS 16
#define HDIM 128

typedef __attribute__((ext_vector_type(8))) short bf16x8;
typedef __attribute__((ext_vector_type(4))) float f32x4;
typedef unsigned short us;

static __device__ __forceinline__ us f2b(float f) {
    union { float f; unsigned u; } x; x.f = f;
    unsigned r = x.u + 0x7fffu + ((x.u >> 16) & 1u);
    return (us)(r >> 16);
}

static __device__ __forceinline__ uint2 pack4(float a, float b, float c, float d) {
    uint2 u;
    u.x = (unsigned)f2b(a) | ((unsigned)f2b(b) << 16);
    u.y = (unsigned)f2b(c) | ((unsigned)f2b(d) << 16);
    return u;
}

// async 16B global->LDS (lds dest must be wave-uniform base; HW adds lane*16)
static __device__ __forceinline__ void gl_lds16(const void* g, void* l) {
    __builtin_amdgcn_global_load_lds(
        (const __attribute__((address_space(1))) void*)g,
        (__attribute__((address_space(3))) void*)l, 16, 0, 0);
}

// ---------------------------------------------------------------------------
// transpose+cast: out[N][K] bf16  <-  in[K][N] f32.  one thread = 8 k-elems.
__global__ void tcast(const float* __restrict__ in, us* __restrict__ out,
                      int N, int K) {
    int id = blockIdx.x * 256 + threadIdx.x;
    int n = id & (N - 1);
    int k0 = (id / N) * 8;
    us t8[8];
#pragma unroll
    for (int j = 0; j < 8; j++) t8[j] = f2b(in[(size_t)(k0 + j) * N + n]);
    *(uint4*)&out[(size_t)n * K + k0] = *(uint4*)t8;
}

// ---------------------------------------------------------------------------
// GEMM: C[M,N] = A[4096,2048] @ Bt[N,2048]^T (+bias). 128x128 tile, BK=32.
// MODE 0: A f32, out = Qh bf16 head-major swizzled, +bias
// MODE 1: A f32 (key for bn=0 / value for bn=128), out = f32 partials (split-K)
// MODE 2: A bf16 via global_load_lds, out = f32 natural, +bias
template <int MODE>
__global__ __launch_bounds__(256, 2) void gemm_k(
    const void* __restrict__ A0, const void* __restrict__ A1,
    const us* __restrict__ Bt, const float* __restrict__ bias,
    void* __restrict__ outp, int N, int k_iters)
{
    __shared__ __align__(16) us As[128 * 32];  // [row][32k], 16B chunks swizzled c^= (row&3)
    __shared__ __align__(16) us Bs[128 * 32];

    const int tid  = threadIdx.x;
    const int lane = tid & 63;
    const int w    = tid >> 6;
    const int lm   = lane & 15;
    const int quad = lane >> 4;
    const int wm = w >> 1, wn = w & 1;
    const int bn = blockIdx.x * 128, bm = blockIdx.y * 128;
    const int k_begin = blockIdx.z * k_iters * 32;

    const float* Af = (MODE == 1) ? (blockIdx.x ? (const float*)A1 : (const float*)A0)
                                  : (const float*)A0;
    const us* Ab = (const us*)A0;

    f32x4 acc[4][4];
#pragma unroll
    for (int i = 0; i < 4; i++)
#pragma unroll
        for (int j = 0; j < 4; j++) acc[i][j] = (f32x4){0.f, 0.f, 0.f, 0.f};

    for (int kk = 0; kk < k_iters; ++kk) {
        const int k0 = k_begin + kk * 32;
        if (MODE == 2) {
            // A: bf16 dma, swizzle applied by gathering the right global chunk
#pragma unroll
            for (int i = 0; i < 2; i++) {
                int sl = i * 256 + tid;
                int row = sl >> 2, cp = sl & 3, c = cp ^ (row & 3);
                gl_lds16(Ab + (size_t)(bm + row) * 2048 + k0 + c * 8,
                         (char*)As + (i * 256 + (tid & 192)) * 16);
            }
        } else {
            // A: f32 -> bf16 VALU staging, b128 LDS writes
            int row = tid >> 1;
            const float* g = Af + (size_t)(bm + row) * 2048 + k0;
#pragma unroll
            for (int cc = 0; cc < 2; cc++) {
                int cp = (tid & 1) * 2 + cc;
                int c = cp ^ (row & 3);
                float4 v0 = *(const float4*)(g + c * 8);
                float4 v1 = *(const float4*)(g + c * 8 + 4);
                us t8[8];
                t8[0] = f2b(v0.x); t8[1] = f2b(v0.y); t8[2] = f2b(v0.z); t8[3] = f2b(v0.w);
                t8[4] = f2b(v1.x); t8[5] = f2b(v1.y); t8[6] = f2b(v1.z); t8[7] = f2b(v1.w);
                *(uint4*)&As[row * 32 + cp * 8] = *(uint4*)t8;
            }
        }
        // B: bf16 dma from Bt[n][k]
#pragma unroll
        for (int i = 0; i < 2; i++) {
            int sl = i * 256 + tid;
            int row = sl >> 2, cp = sl & 3, c = cp ^ (row & 3);
            gl_lds16(Bt + (size_t)(bn + row) * 2048 + k0 + c * 8,
                     (char*)Bs + (i * 256 + (tid & 192)) * 16);
        }
        __syncthreads();

        bf16x8 af[4], bf[4];
#pragma unroll
        for (int mi = 0; mi < 4; mi++) {
            int row = wm * 64 + mi * 16 + lm;
            int cp = quad ^ (row & 3);
            af[mi] = *(const bf16x8*)&As[row * 32 + cp * 8];
        }
#pragma unroll
        for (int ni = 0; ni < 4; ni++) {
            int row = wn * 64 + ni * 16 + lm;
            int cp = quad ^ (row & 3);
            bf[ni] = *(const bf16x8*)&Bs[row * 32 + cp * 8];
        }
#pragma unroll
        for (int mi = 0; mi < 4; mi++)
#pragma unroll
            for (int ni = 0; ni < 4; ni++)
                acc[mi][ni] = __builtin_amdgcn_mfma_f32_16x16x32_bf16(
                    af[mi], bf[ni], acc[mi][ni], 0, 0, 0);
        __syncthreads();
    }

    // epilogue
#pragma unroll
    for (int mi = 0; mi < 4; mi++) {
#pragma unroll
        for (int ni = 0; ni < 4; ni++) {
            int col = bn + wn * 64 + ni * 16 + lm;
#pragma unroll
            for (int r = 0; r < 4; r++) {
                int row = bm + wm * 64 + mi * 16 + quad * 4 + r;
                float v = acc[mi][ni][r];
                if (MODE == 0) {
                    v += bias[col];
                    int b = row >> 11, s = row & 2047;
                    int h = col >> 7, hd = col & 127;
                    size_t addr = (((size_t)(b * 16 + h) * 2048 + s) << 7)
                                  + (((hd >> 3) ^ (s & 7)) << 3) + (hd & 7);
                    ((us*)outp)[addr] = f2b(v);
                } else if (MODE == 1) {
                    float* part = (float*)outp + (size_t)blockIdx.z * 1048576;
                    part[(size_t)row * 256 + col] = v;
                } else {
                    ((float*)outp)[(size_t)row * 2048 + col] = v + bias[col];
                }
            }
        }
    }
}

// ---------------------------------------------------------------------------
// kv_finish: sum 4 split-K partials + bias -> Kb (swizzled) and Vt (tiled+swizzled)
__global__ void kv_finish(const float* __restrict__ part, const float* __restrict__ bk,
                          const float* __restrict__ bv, us* __restrict__ Kb,
                          us* __restrict__ Vt) {
    int id = blockIdx.x * 256 + threadIdx.x;
    int row = id >> 8, n = id & 255;
    float s = part[id] + part[1048576 + id] + part[2097152 + id] + part[3145728 + id];
    int b = row >> 11, t = row & 2047;
    if (n < 128) {
        int hd = n;
        s += bk[hd];
        Kb[((size_t)(b * 2048 + t) << 7) + (((hd >> 3) ^ (t & 7)) << 3) + (hd & 7)] = f2b(s);
    } else {
        int hd = n - 128;
        s += bv[hd];
        // layout [b][t>>5][hd][32t], chunk swizzle c ^= (hd>>1)&3
        size_t addr = (((size_t)(b * 64 + (t >> 5)) * 128 + hd) << 5)
                      + ((((t >> 3) & 3) ^ ((hd >> 1) & 3)) << 3) + (t & 7);
        Vt[addr] = f2b(s);
    }
}

// ---------------------------------------------------------------------------
// MQA flash attention, transposed form. Q-tile 128, KV-tile 32, no-max softmax.
// S^T = K·Q^T (per-lane: 4 consecutive t -> b64 P writes), O^T = V^T·P^T.
__global__ __launch_bounds__(256, 2) void mqa_attn(
    const us* __restrict__ Qh, const us* __restrict__ Kb,
    const us* __restrict__ Vt, us* __restrict__ AO)
{
    __shared__ __align__(16) char smem[65536];
    us* Qs  = (us*)smem;                 // [128][128] swizzled (32KB)
    us* Ksb = (us*)(smem + 32768);       // 2 x [32][128] swizzled (16KB)
    us* Vts = (us*)(smem + 49152);       // [128hd][32t] swizzled (8KB)
    us* Ps  = (us*)(smem + 57344);       // [128q][32t] swizzled (8KB)
    float* Lb = (float*)(smem + 32768);  // aliases Ksb (dead after last S^T)

    const int tid  = threadIdx.x;
    const int lane = tid & 63;
    const int w    = tid >> 6;
    const int lm   = lane & 15;
    const int quad = lane >> 4;
    const int wm = w >> 1, wn = w & 1;
    const int q0 = blockIdx.x * 128;
    const int h  = blockIdx.y;
    const int b  = blockIdx.z;
    const float sc = 0.08838834764831845f;  // 1/sqrt(128)

    const us* Qtile = Qh + (((size_t)(b * 16 + h) * 2048 + q0) << 7);
    const us* Kbase = Kb + ((size_t)b * 2048 << 7);
    const us* Vbase = Vt + (size_t)b * 64 * 4096;

    // stage Q (32KB contiguous), K(0), V(0)
#pragma unroll
    for (int i = 0; i < 8; i++) {
        int sl = w * 512 + i * 64 + lane;
        gl_lds16(Qtile + sl * 8, smem + (w * 512 + i * 64) * 16);
    }
#pragma unroll
    for (int i = 0; i < 2; i++) {
        int sl = w * 128 + i * 64 + lane;
        gl_lds16(Kbase + sl * 8, (char*)Ksb + (w * 128 + i * 64) * 16);
        gl_lds16(Vbase + sl * 8, (char*)Vts + (w * 128 + i * 64) * 16);
    }
    __syncthreads();

    // hoist Q fragments (loop-invariant B-operands): [nt][ks]
    bf16x8 qf[4][4];
#pragma unroll
    for (int nt = 0; nt < 4; nt++)
#pragma unroll
        for (int ks = 0; ks < 4; ks++) {
            int q = wn * 64 + nt * 16 + lm;
            int cp = (ks * 4 + quad) ^ (q & 7);
            qf[nt][ks] = *(const bf16x8*)&Qs[q * 128 + cp * 8];
        }

    f32x4 oacc[4][4];  // [mt hd-tile][nt q-tile]
#pragma unroll
    for (int i = 0; i < 4; i++)
#pragma unroll
        for (int j = 0; j < 4; j++) oacc[i][j] = (f32x4){0.f, 0.f, 0.f, 0.f};
    float lsum[4] = {0.f, 0.f, 0.f, 0.f};

    for (int it = 0; it < 64; ++it) {
        const int p = it & 1;
        const us* Kst = Ksb + p * 4096;

        // S^T(32t x 128q): wave = 1 m-tile (wm) x 4 n-tiles (wn half)
        f32x4 sacc[4];
#pragma unroll
        for (int nt = 0; nt < 4; nt++) sacc[nt] = (f32x4){0.f, 0.f, 0.f, 0.f};
#pragma unroll
        for (int ks = 0; ks < 4; ks++) {
            int t = wm * 16 + lm;
            int cp = (ks * 4 + quad) ^ (lm & 7);
            bf16x8 kf = *(const bf16x8*)&Kst[t * 128 + cp * 8];
#pragma unroll
            for (int nt = 0; nt < 4; nt++)
                sacc[nt] = __builtin_amdgcn_mfma_f32_16x16x32_bf16(
                    kf, qf[nt][ks], sacc[nt], 0, 0, 0);
        }
        // prefetch K(it+1) into other buffer (overlaps exp+PV)
        if (it < 63) {
            const us* kg = Kbase + (it + 1) * 32 * 128;
#pragma unroll
            for (int i = 0; i < 2; i++) {
                int sl = w * 128 + i * 64 + lane;
                gl_lds16(kg + sl * 8, (char*)Ksb + (1 - p) * 8192 + (w * 128 + i * 64) * 16);
            }
        }
        // p = exp(s*scale); lane holds 4 consecutive t -> one b64 write per nt
#pragma unroll
        for (int nt = 0; nt < 4; nt++) {
            int q = wn * 64 + nt * 16 + lm;
            float p0 = __expf(sacc[nt][0] * sc);
            float p1 = __expf(sacc[nt][1] * sc);
            float p2 = __expf(sacc[nt][2] * sc);
            float p3 = __expf(sacc[nt][3] * sc);
            lsum[nt] += (p0 + p1) + (p2 + p3);
            int tb = wm * 16 + quad * 4;
            int cp = (tb >> 3) ^ ((q >> 1) & 3);
            *(uint2*)&Ps[q * 32 + cp * 8 + (tb & 7)] = pack4(p0, p1, p2, p3);
        }
        __syncthreads();  // BAR_A: P visible, K(it+1) drained, V(it) drained

        // O^T += V^T(128hd x 32t) @ P^T(32t x 128q): wave = 4 m-tiles x 4 n-tiles
        bf16x8 vf[4], pf[4];
#pragma unroll
        for (int mt = 0; mt < 4; mt++) {
            int hd = (wm * 4 + mt) * 16 + lm;
            int cp = quad ^ ((hd >> 1) & 3);
            vf[mt] = *(const bf16x8*)&Vts[hd * 32 + cp * 8];
        }
#pragma unroll
        for (int nt = 0; nt < 4; nt++) {
            int q = (wn * 4 + nt) * 16 + lm;
            int cp = quad ^ ((q >> 1) & 3);
            pf[nt] = *(const bf16x8*)&Ps[q * 32 + cp * 8];
        }
#pragma unroll
        for (int mt = 0; mt < 4; mt++)
#pragma unroll
            for (int nt = 0; nt < 4; nt++)
                oacc[mt][nt] = __builtin_amdgcn_mfma_f32_16x16x32_bf16(
                    vf[mt], pf[nt], oacc[mt][nt], 0, 0, 0);
        __syncthreads();  // BAR_B: Vts & Ps free

        if (it < 63) {
            const us* vg = Vbase + (it + 1) * 4096;
#pragma unroll
            for (int i = 0; i < 2; i++) {
                int sl = w * 128 + i * 64 + lane;
                gl_lds16(vg + sl * 8, (char*)Vts + (w * 128 + i * 64) * 16);
            }
        }
    }

    // l reduction: across quads (shfl), then across wm halves (LDS)
#pragma unroll
    for (int nt = 0; nt < 4; nt++) {
        lsum[nt] += __shfl_xor(lsum[nt], 16);
        lsum[nt] += __shfl_xor(lsum[nt], 32);
    }
    if (quad == 0) {
#pragma unroll
        for (int nt = 0; nt < 4; nt++)
            Lb[wm * 128 + wn * 64 + nt * 16 + lm] = lsum[nt];
    }
    __syncthreads();

    // epilogue: O = O^T / l, b64 stores (4 consecutive hd)
#pragma unroll
    for (int nt = 0; nt < 4; nt++) {
        int q = (wn * 4 + nt) * 16 + lm;
        float linv = 1.f / (Lb[q] + Lb[128 + q]);
#pragma unroll
        for (int mt = 0; mt < 4; mt++) {
            int hdb = (wm * 4 + mt) * 16 + quad * 4;
            uint2 u = pack4(oacc[mt][nt][0] * linv, oacc[mt][nt][1] * linv,
                            oacc[mt][nt][2] * linv, oacc[mt][nt][3] * linv);
            *(uint2*)&AO[((size_t)(b * 2048 + q0 + q)) * 2048 + h * 128 + hdb] = u;
        }
    }
}

// ---------------------------------------------------------------------------
extern "C" void kernel_launch(void* const* d_in, const int* in_sizes, int n_in,
                              void* d_out, int out_size, void* d_ws, size_t ws_size,
                              hipStream_t stream) {
    const float* query = (const float*)d_in[0];
    const float* key   = (const float*)d_in[1];
    const float* value = (const float*)d_in[2];
    const float* Wq = (const float*)d_in[3];
    const float* bq = (const float*)d_in[4];
    const float* Wk = (const float*)d_in[5];
    const float* bk = (const float*)d_in[6];
    const float* Wv = (const float*)d_in[7];
    const float* bv = (const float*)d_in[8];
    const float* Wo = (const float*)d_in[9];
    const float* bo = (const float*)d_in[10];
    float* out = (float*)d_out;

    char* ws = (char*)d_ws;
    us*    Wqt  = (us*)ws;                          //  8.39MB (reused for Wot)
    us*    Wkvt = (us*)(ws + 8388608);              //  1.05MB
    us*    Qh   = (us*)(ws + 9437184);              // 16.78MB
    float* part = (float*)(ws + 26214400);          // 16.78MB (reused for AO)
    us*    AO   = (us*)part;
    us*    Kb   = (us*)(ws + 42991616);             //  1.05MB
    us*    Vtb  = (us*)(ws + 44040192);             //  1.05MB

    dim3 blk(256);
    // weight transposes (bf16, [n][k])
    tcast<<<2048, blk, 0, stream>>>(Wq, Wqt, 2048, 2048);
    tcast<<<128,  blk, 0, stream>>>(Wk, Wkvt, 128, 2048);
    tcast<<<128,  blk, 0, stream>>>(Wv, Wkvt + 128 * 2048, 128, 2048);
    // Q projection -> Qh (head-major, swizzled)
    gemm_k<0><<<dim3(16, 32, 1), blk, 0, stream>>>(query, nullptr, Wqt, bq, Qh, 2048, 64);
    // Wo transpose (reuses Wqt region, after Qproj consumed it)
    tcast<<<2048, blk, 0, stream>>>(Wo, Wqt, 2048, 2048);
    // K|V projection, split-K(4) -> partials, then finish -> Kb / Vt
    gemm_k<1><<<dim3(2, 32, 4), blk, 0, stream>>>(key, value, Wkvt, nullptr, part, 256, 16);
    kv_finish<<<4096, blk, 0, stream>>>(part, bk, bv, Kb, Vtb);
    // attention -> AO (bf16 [4096][2048], overwrites partials region)
    mqa_attn<<<dim3(16, 16, 2), blk, 0, stream>>>(Qh, Kb, Vtb, AO);
    // output projection -> out (f32)
    gemm_k<2><<<dim3(16, 32, 1), blk, 0, stream>>>(AO, nullptr, Wqt, bo, out, 2048, 64);
}

// Round 3
// 398.493 us; speedup vs baseline: 3.5586x; 1.0376x over previous
//
#include <hip/hip_runtime.h>
#include <stdint.h>

#define S_LEN 2048
#define EMBED 2048
#define NHEADS 16
#define HDIM 128

typedef __attribute__((ext_vector_type(8))) short bf16x8;
typedef __attribute__((ext_vector_type(4))) float f32x4;
typedef unsigned short us;

static __device__ __forceinline__ us f2b(float f) {
    union { float f; unsigned u; } x; x.f = f;
    unsigned r = x.u + 0x7fffu + ((x.u >> 16) & 1u);
    return (us)(r >> 16);
}

static __device__ __forceinline__ uint2 pack4(float a, float b, float c, float d) {
    uint2 u;
    u.x = (unsigned)f2b(a) | ((unsigned)f2b(b) << 16);
    u.y = (unsigned)f2b(c) | ((unsigned)f2b(d) << 16);
    return u;
}

// async 16B global->LDS; lds dest wave-uniform base, HW adds lane*16
static __device__ __forceinline__ void gl_lds16(const void* g, void* l) {
    __builtin_amdgcn_global_load_lds(
        (const __attribute__((address_space(1))) void*)g,
        (__attribute__((address_space(3))) void*)l, 16, 0, 0);
}

// ---------------------------------------------------------------------------
// GEMM building blocks: 128x128 tile, BK=64, LDS [row][64k] with 16B-chunk
// XOR swizzle (phys_chunk = logical_chunk ^ (row&7)); 4 waves in 2x2.

// stage a 128x64 bf16 tile via DMA (16KB, 4 gl_lds per thread-slot pass)
static __device__ __forceinline__ void dma_tile(const us* __restrict__ g, int k0,
                                                us* dst, int tid) {
#pragma unroll
    for (int i = 0; i < 4; i++) {
        int sl = i * 256 + tid;
        int row = sl >> 3, cp = sl & 7, c = cp ^ (row & 7);
        gl_lds16(g + (size_t)row * 2048 + k0 + c * 8,
                 (char*)dst + (i * 256 + (tid & 192)) * 16);
    }
}

static __device__ __forceinline__ void loadA_f32(const float* __restrict__ g,
                                                 float4 pf[8]) {
#pragma unroll
    for (int i = 0; i < 8; i++) pf[i] = ((const float4*)g)[i];
}

static __device__ __forceinline__ void writeA_f32(us* dst, const float4 pf[8],
                                                  int row, int h) {
#pragma unroll
    for (int cc = 0; cc < 4; cc++) {
        int p = (h * 4 + cc) ^ (row & 7);
        float4 a = pf[cc * 2], b = pf[cc * 2 + 1];
        uint4 u;
        u.x = (unsigned)f2b(a.x) | ((unsigned)f2b(a.y) << 16);
        u.y = (unsigned)f2b(a.z) | ((unsigned)f2b(a.w) << 16);
        u.z = (unsigned)f2b(b.x) | ((unsigned)f2b(b.y) << 16);
        u.w = (unsigned)f2b(b.z) | ((unsigned)f2b(b.w) << 16);
        *(uint4*)&dst[row * 64 + p * 8] = u;
    }
}

static __device__ __forceinline__ void frag_mfma(const us* curA, const us* curB,
                                                 int wm, int wn, int lm, int quad,
                                                 f32x4 acc[4][4]) {
#pragma unroll
    for (int kc = 0; kc < 2; kc++) {
        bf16x8 af[4], bfr[4];
#pragma unroll
        for (int mi = 0; mi < 4; mi++) {
            int row = wm * 64 + mi * 16 + lm;
            int p = (kc * 4 + quad) ^ (row & 7);
            af[mi] = *(const bf16x8*)&curA[row * 64 + p * 8];
        }
#pragma unroll
        for (int ni = 0; ni < 4; ni++) {
            int row = wn * 64 + ni * 16 + lm;
            int p = (kc * 4 + quad) ^ (row & 7);
            bfr[ni] = *(const bf16x8*)&curB[row * 64 + p * 8];
        }
#pragma unroll
        for (int mi = 0; mi < 4; mi++)
#pragma unroll
            for (int ni = 0; ni < 4; ni++)
                acc[mi][ni] = __builtin_amdgcn_mfma_f32_16x16x32_bf16(
                    af[mi], bfr[ni], acc[mi][ni], 0, 0, 0);
    }
}

// ---------------------------------------------------------------------------
// tcast3: Wq/Wk/Wv f32 [k][n] -> bf16 [n][k] in one launch
__global__ void tcast3(const float* __restrict__ Wq, const float* __restrict__ Wk,
                       const float* __restrict__ Wv, us* __restrict__ Wqt,
                       us* __restrict__ Wkvt) {
    int b = blockIdx.x;
    const float* in; us* out; int N, rel;
    if (b < 2048)      { in = Wq; out = Wqt;  N = 2048; rel = b; }
    else if (b < 2176) { in = Wk; out = Wkvt; N = 128;  rel = b - 2048; }
    else               { in = Wv; out = Wkvt + (size_t)128 * 2048; N = 128; rel = b - 2176; }
    int id = rel * 256 + threadIdx.x;
    int n = id & (N - 1), k0 = (id / N) * 8;
    us t8[8];
#pragma unroll
    for (int j = 0; j < 8; j++) t8[j] = f2b(in[(size_t)(k0 + j) * N + n]);
    *(uint4*)&out[(size_t)n * 2048 + k0] = *(uint4*)t8;
}

// ---------------------------------------------------------------------------
// fused Q + KV(split-K 4) projection. blocks [0,512): Q tiles; [512,768): KV.
__global__ __launch_bounds__(256, 2) void proj_qkv(
    const float* __restrict__ query, const float* __restrict__ key,
    const float* __restrict__ value, const us* __restrict__ Wqt,
    const us* __restrict__ Wkvt, const float* __restrict__ bq,
    us* __restrict__ Qh, float* __restrict__ part)
{
    __shared__ __align__(16) us A0[128 * 64], A1[128 * 64];
    __shared__ __align__(16) us B0[128 * 64], B1[128 * 64];

    const int tid = threadIdx.x;
    const int lane = tid & 63, w = tid >> 6, lm = lane & 15, quad = lane >> 4;
    const int wm = w >> 1, wn = w & 1;
    const int id = blockIdx.x;

    const float* Atile; const us* Btile;
    int bm, bn, kbeg, iters, isQ, z = 0;
    if (id < 512) {
        isQ = 1; bn = (id & 15) * 128; bm = (id >> 4) * 128;
        Atile = query + (size_t)bm * 2048;
        Btile = Wqt + (size_t)bn * 2048;
        kbeg = 0; iters = 32;
    } else {
        int e = id - 512; isQ = 0;
        z = e >> 6; int r = e & 63; int isV = r & 1;
        bm = (r >> 1) * 128; bn = isV * 128;
        Atile = (isV ? value : key) + (size_t)bm * 2048;
        Btile = Wkvt + (size_t)bn * 2048;
        kbeg = z * 512; iters = 8;
    }
    const int arow = tid >> 1, h = tid & 1;
    const float* Ag = Atile + (size_t)arow * 2048 + h * 32;

    f32x4 acc[4][4];
#pragma unroll
    for (int i = 0; i < 4; i++)
#pragma unroll
        for (int j = 0; j < 4; j++) acc[i][j] = (f32x4){0.f, 0.f, 0.f, 0.f};

    float4 pf[8];
    // prologue: stage tile 0 into A0/B0  (A loads first, then B-DMA, so the
    // convert's vmcnt wait leaves B-DMA in flight)
    loadA_f32(Ag + kbeg, pf);
    dma_tile(Btile, kbeg, B0, tid);
    writeA_f32(A0, pf, arow, h);

    for (int kk = 0; kk < iters; kk += 2) {
        const int k1 = kbeg + (kk + 1) * 64;
        const int k2 = kbeg + (kk + 2) * 64;
        // even sub-iter: read 0, prefetch into 1
        __syncthreads();
        if (kk + 1 < iters) { loadA_f32(Ag + k1, pf); dma_tile(Btile, k1, B1, tid); }
        frag_mfma(A0, B0, wm, wn, lm, quad, acc);
        if (kk + 1 < iters) writeA_f32(A1, pf, arow, h);
        // odd sub-iter: read 1, prefetch into 0
        __syncthreads();
        if (kk + 2 < iters) { loadA_f32(Ag + k2, pf); dma_tile(Btile, k2, B0, tid); }
        frag_mfma(A1, B1, wm, wn, lm, quad, acc);
        if (kk + 2 < iters) writeA_f32(A0, pf, arow, h);
    }

    if (isQ) {
#pragma unroll
        for (int mi = 0; mi < 4; mi++)
#pragma unroll
            for (int ni = 0; ni < 4; ni++) {
                int col = bn + wn * 64 + ni * 16 + lm;
                float bv = bq[col];
#pragma unroll
                for (int r = 0; r < 4; r++) {
                    int row = bm + wm * 64 + mi * 16 + quad * 4 + r;
                    float v = acc[mi][ni][r] + bv;
                    int b = row >> 11, s = row & 2047;
                    int hh = col >> 7, hd = col & 127;
                    size_t addr = (((size_t)(b * 16 + hh) * 2048 + s) << 7)
                                  + (((hd >> 3) ^ (s & 7)) << 3) + (hd & 7);
                    Qh[addr] = f2b(v);
                }
            }
    } else {
        float* pp = part + (size_t)z * 1048576;
#pragma unroll
        for (int mi = 0; mi < 4; mi++)
#pragma unroll
            for (int ni = 0; ni < 4; ni++) {
                int col = bn + wn * 64 + ni * 16 + lm;
#pragma unroll
                for (int r = 0; r < 4; r++) {
                    int row = bm + wm * 64 + mi * 16 + quad * 4 + r;
                    pp[(size_t)row * 256 + col] = acc[mi][ni][r];
                }
            }
    }
}

// ---------------------------------------------------------------------------
// finish_wot: blocks [0,2048) transpose+cast Wo; [2048,6144) kv split-K reduce
__global__ void finish_wot(const float* __restrict__ part, const float* __restrict__ bk,
                           const float* __restrict__ bv, us* __restrict__ Kb,
                           us* __restrict__ Vt, const float* __restrict__ Wo,
                           us* __restrict__ Wot) {
    int b = blockIdx.x;
    if (b < 2048) {
        int id = b * 256 + threadIdx.x;
        int n = id & 2047, k0 = (id >> 11) * 8;
        us t8[8];
#pragma unroll
        for (int j = 0; j < 8; j++) t8[j] = f2b(Wo[(size_t)(k0 + j) * 2048 + n]);
        *(uint4*)&Wot[(size_t)n * 2048 + k0] = *(uint4*)t8;
    } else {
        int id = (b - 2048) * 256 + threadIdx.x;
        int row = id >> 8, n = id & 255;
        float s = part[id] + part[1048576 + id] + part[2097152 + id] + part[3145728 + id];
        int bb = row >> 11, t = row & 2047;
        if (n < 128) {
            int hd = n;
            s += bk[hd];
            Kb[((size_t)(bb * 2048 + t) << 7) + (((hd >> 3) ^ (t & 7)) << 3) + (hd & 7)] = f2b(s);
        } else {
            int hd = n - 128;
            s += bv[hd];
            size_t addr = (((size_t)(bb * 64 + (t >> 5)) * 128 + hd) << 5)
                          + ((((t >> 3) & 3) ^ ((hd >> 1) & 3)) << 3) + (t & 7);
            Vt[addr] = f2b(s);
        }
    }
}

// ---------------------------------------------------------------------------
// MQA flash attention, transposed form (unchanged from R1).
__global__ __launch_bounds__(256, 2) void mqa_attn(
    const us* __restrict__ Qh, const us* __restrict__ Kb,
    const us* __restrict__ Vt, us* __restrict__ AO)
{
    __shared__ __align__(16) char smem[65536];
    us* Qs  = (us*)smem;
    us* Ksb = (us*)(smem + 32768);
    us* Vts = (us*)(smem + 49152);
    us* Ps  = (us*)(smem + 57344);
    float* Lb = (float*)(smem + 32768);

    const int tid  = threadIdx.x;
    const int lane = tid & 63;
    const int w    = tid >> 6;
    const int lm   = lane & 15;
    const int quad = lane >> 4;
    const int wm = w >> 1, wn = w & 1;
    const int q0 = blockIdx.x * 128;
    const int h  = blockIdx.y;
    const int b  = blockIdx.z;
    const float sc = 0.08838834764831845f;

    const us* Qtile = Qh + (((size_t)(b * 16 + h) * 2048 + q0) << 7);
    const us* Kbase = Kb + ((size_t)b * 2048 << 7);
    const us* Vbase = Vt + (size_t)b * 64 * 4096;

#pragma unroll
    for (int i = 0; i < 8; i++) {
        int sl = w * 512 + i * 64 + lane;
        gl_lds16(Qtile + sl * 8, smem + (w * 512 + i * 64) * 16);
    }
#pragma unroll
    for (int i = 0; i < 2; i++) {
        int sl = w * 128 + i * 64 + lane;
        gl_lds16(Kbase + sl * 8, (char*)Ksb + (w * 128 + i * 64) * 16);
        gl_lds16(Vbase + sl * 8, (char*)Vts + (w * 128 + i * 64) * 16);
    }
    __syncthreads();

    bf16x8 qf[4][4];
#pragma unroll
    for (int nt = 0; nt < 4; nt++)
#pragma unroll
        for (int ks = 0; ks < 4; ks++) {
            int q = wn * 64 + nt * 16 + lm;
            int cp = (ks * 4 + quad) ^ (q & 7);
            qf[nt][ks] = *(const bf16x8*)&Qs[q * 128 + cp * 8];
        }

    f32x4 oacc[4][4];
#pragma unroll
    for (int i = 0; i < 4; i++)
#pragma unroll
        for (int j = 0; j < 4; j++) oacc[i][j] = (f32x4){0.f, 0.f, 0.f, 0.f};
    float lsum[4] = {0.f, 0.f, 0.f, 0.f};

    for (int it = 0; it < 64; ++it) {
        const int p = it & 1;
        const us* Kst = Ksb + p * 4096;

        f32x4 sacc[4];
#pragma unroll
        for (int nt = 0; nt < 4; nt++) sacc[nt] = (f32x4){0.f, 0.f, 0.f, 0.f};
#pragma unroll
        for (int ks = 0; ks < 4; ks++) {
            int t = wm * 16 + lm;
            int cp = (ks * 4 + quad) ^ (lm & 7);
            bf16x8 kf = *(const bf16x8*)&Kst[t * 128 + cp * 8];
#pragma unroll
            for (int nt = 0; nt < 4; nt++)
                sacc[nt] = __builtin_amdgcn_mfma_f32_16x16x32_bf16(
                    kf, qf[nt][ks], sacc[nt], 0, 0, 0);
        }
        if (it < 63) {
            const us* kg = Kbase + (it + 1) * 32 * 128;
#pragma unroll
            for (int i = 0; i < 2; i++) {
                int sl = w * 128 + i * 64 + lane;
                gl_lds16(kg + sl * 8, (char*)Ksb + (1 - p) * 8192 + (w * 128 + i * 64) * 16);
            }
        }
#pragma unroll
        for (int nt = 0; nt < 4; nt++) {
            int q = wn * 64 + nt * 16 + lm;
            float p0 = __expf(sacc[nt][0] * sc);
            float p1 = __expf(sacc[nt][1] * sc);
            float p2 = __expf(sacc[nt][2] * sc);
            float p3 = __expf(sacc[nt][3] * sc);
            lsum[nt] += (p0 + p1) + (p2 + p3);
            int tb = wm * 16 + quad * 4;
            int cp = (tb >> 3) ^ ((q >> 1) & 3);
            *(uint2*)&Ps[q * 32 + cp * 8 + (tb & 7)] = pack4(p0, p1, p2, p3);
        }
        __syncthreads();

        bf16x8 vf[4], pfr[4];
#pragma unroll
        for (int mt = 0; mt < 4; mt++) {
            int hd = (wm * 4 + mt) * 16 + lm;
            int cp = quad ^ ((hd >> 1) & 3);
            vf[mt] = *(const bf16x8*)&Vts[hd * 32 + cp * 8];
        }
#pragma unroll
        for (int nt = 0; nt < 4; nt++) {
            int q = (wn * 4 + nt) * 16 + lm;
            int cp = quad ^ ((q >> 1) & 3);
            pfr[nt] = *(const bf16x8*)&Ps[q * 32 + cp * 8];
        }
#pragma unroll
        for (int mt = 0; mt < 4; mt++)
#pragma unroll
            for (int nt = 0; nt < 4; nt++)
                oacc[mt][nt] = __builtin_amdgcn_mfma_f32_16x16x32_bf16(
                    vf[mt], pfr[nt], oacc[mt][nt], 0, 0, 0);
        __syncthreads();

        if (it < 63) {
            const us* vg = Vbase + (it + 1) * 4096;
#pragma unroll
            for (int i = 0; i < 2; i++) {
                int sl = w * 128 + i * 64 + lane;
                gl_lds16(vg + sl * 8, (char*)Vts + (w * 128 + i * 64) * 16);
            }
        }
    }

#pragma unroll
    for (int nt = 0; nt < 4; nt++) {
        lsum[nt] += __shfl_xor(lsum[nt], 16);
        lsum[nt] += __shfl_xor(lsum[nt], 32);
    }
    if (quad == 0) {
#pragma unroll
        for (int nt = 0; nt < 4; nt++)
            Lb[wm * 128 + wn * 64 + nt * 16 + lm] = lsum[nt];
    }
    __syncthreads();

#pragma unroll
    for (int nt = 0; nt < 4; nt++) {
        int q = (wn * 4 + nt) * 16 + lm;
        float linv = 1.f / (Lb[q] + Lb[128 + q]);
#pragma unroll
        for (int mt = 0; mt < 4; mt++) {
            int hdb = (wm * 4 + mt) * 16 + quad * 4;
            uint2 u = pack4(oacc[mt][nt][0] * linv, oacc[mt][nt][1] * linv,
                            oacc[mt][nt][2] * linv, oacc[mt][nt][3] * linv);
            *(uint2*)&AO[((size_t)(b * 2048 + q0 + q)) * 2048 + h * 128 + hdb] = u;
        }
    }
}

// ---------------------------------------------------------------------------
// output projection: AO bf16 @ Wot^T + bo -> f32, pipelined dbuf pure-DMA
__global__ __launch_bounds__(256, 2) void oproj(
    const us* __restrict__ AO, const us* __restrict__ Wot,
    const float* __restrict__ bo, float* __restrict__ out)
{
    __shared__ __align__(16) us A0[128 * 64], A1[128 * 64];
    __shared__ __align__(16) us B0[128 * 64], B1[128 * 64];

    const int tid = threadIdx.x;
    const int lane = tid & 63, w = tid >> 6, lm = lane & 15, quad = lane >> 4;
    const int wm = w >> 1, wn = w & 1;
    const int bn = blockIdx.x * 128, bm = blockIdx.y * 128;
    const us* Atile = AO + (size_t)bm * 2048;
    const us* Btile = Wot + (size_t)bn * 2048;

    f32x4 acc[4][4];
#pragma unroll
    for (int i = 0; i < 4; i++)
#pragma unroll
        for (int j = 0; j < 4; j++) acc[i][j] = (f32x4){0.f, 0.f, 0.f, 0.f};

    dma_tile(Atile, 0, A0, tid);
    dma_tile(Btile, 0, B0, tid);

    for (int kk = 0; kk < 32; kk += 2) {
        __syncthreads();
        if (kk + 1 < 32) { dma_tile(Atile, (kk + 1) * 64, A1, tid);
                           dma_tile(Btile, (kk + 1) * 64, B1, tid); }
        frag_mfma(A0, B0, wm, wn, lm, quad, acc);
        __syncthreads();
        if (kk + 2 < 32) { dma_tile(Atile, (kk + 2) * 64, A0, tid);
                           dma_tile(Btile, (kk + 2) * 64, B0, tid); }
        frag_mfma(A1, B1, wm, wn, lm, quad, acc);
    }

#pragma unroll
    for (int mi = 0; mi < 4; mi++)
#pragma unroll
        for (int ni = 0; ni < 4; ni++) {
            int col = bn + wn * 64 + ni * 16 + lm;
            float bv = bo[col];
#pragma unroll
            for (int r = 0; r < 4; r++) {
                int row = bm + wm * 64 + mi * 16 + quad * 4 + r;
                out[(size_t)row * 2048 + col] = acc[mi][ni][r] + bv;
            }
        }
}

// ---------------------------------------------------------------------------
extern "C" void kernel_launch(void* const* d_in, const int* in_sizes, int n_in,
                              void* d_out, int out_size, void* d_ws, size_t ws_size,
                              hipStream_t stream) {
    const float* query = (const float*)d_in[0];
    const float* key   = (const float*)d_in[1];
    const float* value = (const float*)d_in[2];
    const float* Wq = (const float*)d_in[3];
    const float* bq = (const float*)d_in[4];
    const float* Wk = (const float*)d_in[5];
    const float* bk = (const float*)d_in[6];
    const float* Wv = (const float*)d_in[7];
    const float* bv = (const float*)d_in[8];
    const float* Wo = (const float*)d_in[9];
    const float* bo = (const float*)d_in[10];
    float* out = (float*)d_out;

    char* ws = (char*)d_ws;
    us*    Wqt  = (us*)ws;                  //  8.39MB (reused for Wot)
    us*    Wot  = Wqt;
    us*    Wkvt = (us*)(ws + 8388608);      //  1.05MB
    us*    Qh   = (us*)(ws + 9437184);      // 16.78MB
    float* part = (float*)(ws + 26214400);  // 16.78MB (reused for AO)
    us*    AO   = (us*)part;
    us*    Kb   = (us*)(ws + 42991616);     //  1.05MB
    us*    Vtb  = (us*)(ws + 44040192);     //  1.05MB

    dim3 blk(256);
    tcast3<<<2304, blk, 0, stream>>>(Wq, Wk, Wv, Wqt, Wkvt);
    proj_qkv<<<768, blk, 0, stream>>>(query, key, value, Wqt, Wkvt, bq, Qh, part);
    finish_wot<<<6144, blk, 0, stream>>>(part, bk, bv, Kb, Vtb, Wo, Wot);
    mqa_attn<<<dim3(16, 16, 2), blk, 0, stream>>>(Qh, Kb, Vtb, AO);
    oproj<<<dim3(16, 32), blk, 0, stream>>>(AO, Wot, bo, out);
}